// Round 1
// baseline (1784.032 us; speedup 1.0000x reference)
//
#include <hip/hip_runtime.h>
#include <cstdint>
#include <cstddef>

#define Gn   3040
#define An   100
#define TOKn 43
#define FSn  75
#define NFn  512
#define XC   384

// ============================================================================
// K1: fused per-graph smile GCN.  One 256-thread block per graph.
//   EW = tok_emb @ Wm1[g]            (43x128, LDS)
//   g1 = adj^T @ EW[tok]             (100x128, regs -> LDS, overwrites EW)
//   f2 = g1 @ Wm2[g]                 (100x128, regs -> LDS, overwrites g1)
//   h2 = adj^T @ f2 ; emb = max_b h2 -> xc[:,384:512]
// ============================================================================
template<int NB, bool GATHER>
__device__ __forceinline__ void adjT_mm(const float* __restrict__ adjg,
                                        const float* __restrict__ src,
                                        const int* __restrict__ sTok,
                                        int h, int b0, float* acc)
{
  for (int a = 0; a < An; ++a) {
    float e;
    if (GATHER) e = src[sTok[a] * 128 + h];
    else        e = src[a * 128 + h];
    const float* arow = adjg + a * An + b0;
    #pragma unroll
    for (int q = 0; q < NB / 4; ++q) {
      float4 v = *(const float4*)(arow + 4 * q);
      acc[4*q+0] = fmaf(v.x, e, acc[4*q+0]);
      acc[4*q+1] = fmaf(v.y, e, acc[4*q+1]);
      acc[4*q+2] = fmaf(v.z, e, acc[4*q+2]);
      acc[4*q+3] = fmaf(v.w, e, acc[4*q+3]);
    }
  }
}

__global__ __launch_bounds__(256, 2) void smile_kernel(
    const float* __restrict__ mol_adj, const int* __restrict__ enc,
    const float* __restrict__ tok_emb, const float* __restrict__ Wm1,
    const float* __restrict__ Wm2, float* __restrict__ xc)
{
  __shared__ float sX[An * 128];   // time-multiplexed: EW (rows<43) -> g1 -> f2
  __shared__ float sMax[256];
  __shared__ int   sTok[An];

  const int g   = blockIdx.x;
  const int t   = threadIdx.x;
  if (t < An) sTok[t] = enc[g * An + t];
  const int h   = t & 127;
  const int grp = t >> 7;          // 0: b in [0,52), 1: b in [52,100)

  // ---- stage A: EW[r][h], r<43 ----
  {
    const float* W1 = Wm1 + (size_t)g * (FSn * 128);
    float acc[22];
    #pragma unroll
    for (int j = 0; j < 22; ++j) acc[j] = 0.f;
    const int rbase = grp * 22;
    for (int f = 0; f < FSn; ++f) {
      float w = W1[f * 128 + h];
      #pragma unroll
      for (int j = 0; j < 22; ++j) {
        int r = rbase + j; if (r > TOKn - 1) r = TOKn - 1;   // clamp (guarded write)
        acc[j] = fmaf(tok_emb[r * FSn + f], w, acc[j]);
      }
    }
    #pragma unroll
    for (int j = 0; j < 22; ++j) {
      int r = rbase + j;
      if (r < TOKn) sX[r * 128 + h] = acc[j];
    }
  }
  __syncthreads();   // EW + sTok visible

  const float* adjg = mol_adj + (size_t)g * (An * An);
  const int b0 = grp ? 52 : 0;
  const int nb = grp ? 48 : 52;

  // ---- stage B: g1 = adj^T @ EW[tok] ----
  float accB[52];
  #pragma unroll
  for (int j = 0; j < 52; ++j) accB[j] = 0.f;
  if (grp == 0) adjT_mm<52, true>(adjg, sX, sTok, h, 0,  accB);
  else          adjT_mm<48, true>(adjg, sX, sTok, h, 52, accB);
  __syncthreads();   // all EW reads done before overwrite
  #pragma unroll
  for (int j = 0; j < 52; ++j)
    if (j < nb) sX[(b0 + j) * 128 + h] = accB[j];
  __syncthreads();

  // ---- stage C: f2 = g1 @ Wm2[g] ----
  {
    const int l   = t & 63;
    const int w4  = t >> 6;       // wave id 0..3 -> b quarter
    const int cb0 = w4 * 25;
    const int k2  = 2 * l;
    float accC[50];
    #pragma unroll
    for (int j = 0; j < 50; ++j) accC[j] = 0.f;
    const float* W2 = Wm2 + (size_t)g * (128 * 128);
    for (int hh = 0; hh < 128; hh += 4) {
      float2 wv0 = *(const float2*)&W2[(hh + 0) * 128 + k2];
      float2 wv1 = *(const float2*)&W2[(hh + 1) * 128 + k2];
      float2 wv2 = *(const float2*)&W2[(hh + 2) * 128 + k2];
      float2 wv3 = *(const float2*)&W2[(hh + 3) * 128 + k2];
      #pragma unroll
      for (int j = 0; j < 25; ++j) {
        float4 xv = *(const float4*)&sX[(cb0 + j) * 128 + hh];
        accC[2*j  ] = fmaf(xv.x, wv0.x, accC[2*j  ]);
        accC[2*j+1] = fmaf(xv.x, wv0.y, accC[2*j+1]);
        accC[2*j  ] = fmaf(xv.y, wv1.x, accC[2*j  ]);
        accC[2*j+1] = fmaf(xv.y, wv1.y, accC[2*j+1]);
        accC[2*j  ] = fmaf(xv.z, wv2.x, accC[2*j  ]);
        accC[2*j+1] = fmaf(xv.z, wv2.y, accC[2*j+1]);
        accC[2*j  ] = fmaf(xv.w, wv3.x, accC[2*j  ]);
        accC[2*j+1] = fmaf(xv.w, wv3.y, accC[2*j+1]);
      }
    }
    __syncthreads();   // all g1 reads done before overwrite
    #pragma unroll
    for (int j = 0; j < 25; ++j)
      *(float2*)&sX[(cb0 + j) * 128 + k2] = make_float2(accC[2*j], accC[2*j+1]);
  }
  __syncthreads();

  // ---- stage D: h2 = adj^T @ f2, then max over b ----
  float accD[52];
  #pragma unroll
  for (int j = 0; j < 52; ++j) accD[j] = 0.f;
  if (grp == 0) adjT_mm<52, false>(adjg, sX, sTok, h, 0,  accD);
  else          adjT_mm<48, false>(adjg, sX, sTok, h, 52, accD);
  {
    float m = -3.4e38f;
    #pragma unroll
    for (int j = 0; j < 52; ++j)
      if (j < nb) m = fmaxf(m, accD[j]);
    sMax[t] = m;
  }
  __syncthreads();
  if (t < 128) {
    float v = fmaxf(sMax[t], sMax[128 + t]);
    xc[(size_t)g * NFn + XC + t] = v;
  }
}

// ============================================================================
// gemm64: C[M,N] = A[M,K] @ B[K,N]  (lda=K, ldb=ldc=N), optional relu.
// blockIdx.z selects (A0,B0,C0) vs (A1,B1,C1) for batched pos/neg launches.
// Requires K % 16 == 0, N % 64 == 0. M guarded.
// ============================================================================
__global__ __launch_bounds__(256, 2) void gemm64_kernel(
    const float* __restrict__ A0, const float* __restrict__ A1,
    const float* __restrict__ B0, const float* __restrict__ B1,
    float* __restrict__ C0, float* __restrict__ C1,
    int M, int N, int K, int relu)
{
  const float* A = blockIdx.z ? A1 : A0;
  const float* B = blockIdx.z ? B1 : B0;
  float*       C = blockIdx.z ? C1 : C0;

  __shared__ float As[16][68];
  __shared__ float Bs[16][68];

  const int t  = threadIdx.x;
  const int m0 = blockIdx.x * 64, n0 = blockIdx.y * 64;
  const int tx = t & 15, ty = t >> 4;
  const int am = t >> 2,  ak = (t & 3) * 4;   // A-tile load coords (64x16)
  const int bk = t >> 4,  bn = (t & 15) * 4;  // B-tile load coords (16x64)

  float acc[4][4];
  #pragma unroll
  for (int i = 0; i < 4; ++i)
    #pragma unroll
    for (int j = 0; j < 4; ++j) acc[i][j] = 0.f;

  for (int k0 = 0; k0 < K; k0 += 16) {
    float4 av = make_float4(0.f, 0.f, 0.f, 0.f);
    if (m0 + am < M) av = *(const float4*)&A[(size_t)(m0 + am) * K + k0 + ak];
    float4 bv = *(const float4*)&B[(size_t)(k0 + bk) * N + n0 + bn];
    __syncthreads();
    As[ak + 0][am] = av.x; As[ak + 1][am] = av.y;
    As[ak + 2][am] = av.z; As[ak + 3][am] = av.w;
    *(float4*)&Bs[bk][bn] = bv;
    __syncthreads();
    #pragma unroll
    for (int kk = 0; kk < 16; ++kk) {
      float4 a4 = *(const float4*)&As[kk][ty * 4];
      float4 b4 = *(const float4*)&Bs[kk][tx * 4];
      const float aa[4] = {a4.x, a4.y, a4.z, a4.w};
      const float bb[4] = {b4.x, b4.y, b4.z, b4.w};
      #pragma unroll
      for (int i = 0; i < 4; ++i)
        #pragma unroll
        for (int j = 0; j < 4; ++j)
          acc[i][j] = fmaf(aa[i], bb[j], acc[i][j]);
    }
  }
  #pragma unroll
  for (int i = 0; i < 4; ++i) {
    int m = m0 + ty * 4 + i;
    if (m < M) {
      float4 v = make_float4(acc[i][0], acc[i][1], acc[i][2], acc[i][3]);
      if (relu) {
        v.x = fmaxf(v.x, 0.f); v.y = fmaxf(v.y, 0.f);
        v.z = fmaxf(v.z, 0.f); v.w = fmaxf(v.w, 0.f);
      }
      *(float4*)&C[(size_t)m * N + n0 + tx * 4] = v;
    }
  }
}

// ============================================================================
// gemm128: 128x128 tile, 8x8 per thread.
//  SPLIT: blockIdx.z = s*2+pair; C = Cpair + s*M*N, K chunked by 768.
//  BT:    C = A @ B^T with B stored [N,K] (decoder).
// ============================================================================
template<bool BT, bool SPLIT>
__global__ __launch_bounds__(256, 2) void gemm128_kernel(
    const float* __restrict__ A0, const float* __restrict__ A1,
    const float* __restrict__ B0, const float* __restrict__ B1,
    float* __restrict__ C0, float* __restrict__ C1,
    int M, int N, int K)
{
  const int z = blockIdx.z;
  int pair, k0base, kend;
  if (SPLIT) {
    pair = z & 1;
    int s = z >> 1;
    k0base = s * 768;
    kend = k0base + 768; if (kend > K) kend = K;
  } else { pair = z; k0base = 0; kend = K; }

  const float* A = pair ? A1 : A0;
  const float* B = pair ? B1 : B0;
  float* C;
  if (SPLIT) C = (pair ? C1 : C0) + (size_t)(z >> 1) * M * N;
  else       C = pair ? C1 : C0;

  __shared__ float As[16][132];
  __shared__ float Bs[16][132];

  const int t   = threadIdx.x;
  const int m0  = blockIdx.x * 128, n0 = blockIdx.y * 128;
  const int tx  = t & 15, ty = t >> 4;
  const int tn0 = tx * 8, tm0 = ty * 8;
  const int lm  = t >> 1, lk = (t & 1) * 8;    // A (and BT-B) load coords
  const int bkr = t >> 4, bnr = (t & 15) * 8;  // NN-B load coords

  float acc[8][8];
  #pragma unroll
  for (int i = 0; i < 8; ++i)
    #pragma unroll
    for (int j = 0; j < 8; ++j) acc[i][j] = 0.f;

  for (int k0 = k0base; k0 < kend; k0 += 16) {
    float4 a0v = make_float4(0.f,0.f,0.f,0.f), a1v = a0v;
    if (m0 + lm < M) {
      a0v = *(const float4*)&A[(size_t)(m0 + lm) * K + k0 + lk];
      a1v = *(const float4*)&A[(size_t)(m0 + lm) * K + k0 + lk + 4];
    }
    float4 b0v = make_float4(0.f,0.f,0.f,0.f), b1v = b0v;
    if (BT) {
      if (n0 + lm < N) {
        b0v = *(const float4*)&B[(size_t)(n0 + lm) * K + k0 + lk];
        b1v = *(const float4*)&B[(size_t)(n0 + lm) * K + k0 + lk + 4];
      }
    } else {
      b0v = *(const float4*)&B[(size_t)(k0 + bkr) * N + n0 + bnr];
      b1v = *(const float4*)&B[(size_t)(k0 + bkr) * N + n0 + bnr + 4];
    }
    __syncthreads();
    As[lk + 0][lm] = a0v.x; As[lk + 1][lm] = a0v.y;
    As[lk + 2][lm] = a0v.z; As[lk + 3][lm] = a0v.w;
    As[lk + 4][lm] = a1v.x; As[lk + 5][lm] = a1v.y;
    As[lk + 6][lm] = a1v.z; As[lk + 7][lm] = a1v.w;
    if (BT) {
      Bs[lk + 0][lm] = b0v.x; Bs[lk + 1][lm] = b0v.y;
      Bs[lk + 2][lm] = b0v.z; Bs[lk + 3][lm] = b0v.w;
      Bs[lk + 4][lm] = b1v.x; Bs[lk + 5][lm] = b1v.y;
      Bs[lk + 6][lm] = b1v.z; Bs[lk + 7][lm] = b1v.w;
    } else {
      *(float4*)&Bs[bkr][bnr]     = b0v;
      *(float4*)&Bs[bkr][bnr + 4] = b1v;
    }
    __syncthreads();
    #pragma unroll
    for (int kk = 0; kk < 16; ++kk) {
      float4 x0 = *(const float4*)&As[kk][tm0];
      float4 x1 = *(const float4*)&As[kk][tm0 + 4];
      float4 y0 = *(const float4*)&Bs[kk][tn0];
      float4 y1 = *(const float4*)&Bs[kk][tn0 + 4];
      const float aa[8] = {x0.x,x0.y,x0.z,x0.w,x1.x,x1.y,x1.z,x1.w};
      const float bb[8] = {y0.x,y0.y,y0.z,y0.w,y1.x,y1.y,y1.z,y1.w};
      #pragma unroll
      for (int i = 0; i < 8; ++i)
        #pragma unroll
        for (int j = 0; j < 8; ++j)
          acc[i][j] = fmaf(aa[i], bb[j], acc[i][j]);
    }
  }
  const bool nvalid = (n0 + tn0) < N;   // per-thread 8-col group all-or-nothing
  #pragma unroll
  for (int i = 0; i < 8; ++i) {
    int m = m0 + tm0 + i;
    if (m < M && nvalid) {
      float4 v0 = make_float4(acc[i][0], acc[i][1], acc[i][2], acc[i][3]);
      float4 v1 = make_float4(acc[i][4], acc[i][5], acc[i][6], acc[i][7]);
      *(float4*)&C[(size_t)m * N + n0 + tn0]     = v0;
      *(float4*)&C[(size_t)m * N + n0 + tn0 + 4] = v1;
    }
  }
}

// ============================================================================
// reduce over split-K partials (+ optional relu), strided dest for z-assembly
// ============================================================================
__global__ void reduce_kernel(const float* __restrict__ part, float* __restrict__ dst,
                              int S, int M, int N, int ldc, int coff, int relu)
{
  int i = blockIdx.x * blockDim.x + threadIdx.x;    // float4 index
  int total = M * (N / 4);
  if (i >= total) return;
  int r = i / (N / 4), c = (i % (N / 4)) * 4;
  float4 s = make_float4(0.f, 0.f, 0.f, 0.f);
  for (int j = 0; j < S; ++j) {
    float4 v = *(const float4*)&part[(size_t)j * M * N + (size_t)r * N + c];
    s.x += v.x; s.y += v.y; s.z += v.z; s.w += v.w;
  }
  if (relu) {
    s.x = fmaxf(s.x, 0.f); s.y = fmaxf(s.y, 0.f);
    s.z = fmaxf(s.z, 0.f); s.w = fmaxf(s.w, 0.f);
  }
  *(float4*)&dst[(size_t)r * ldc + coff + c] = s;
}

__global__ void copyx_kernel(const float* __restrict__ x, float* __restrict__ xc)
{
  int i = blockIdx.x * blockDim.x + threadIdx.x;    // float4 index over G*384/4
  int total = Gn * (XC / 4);
  if (i >= total) return;
  int r = i / (XC / 4), c = (i % (XC / 4)) * 4;
  *(float4*)&xc[(size_t)r * NFn + c] = *(const float4*)&x[(size_t)r * XC + c];
}

// ============================================================================
extern "C" void kernel_launch(void* const* d_in, const int* in_sizes, int n_in,
                              void* d_out, int out_size, void* d_ws, size_t ws_size,
                              hipStream_t stream)
{
  const float* x       = (const float*)d_in[0];
  const float* adj_pos = (const float*)d_in[1];
  const float* adj_neg = (const float*)d_in[2];
  const float* mol_adj = (const float*)d_in[3];
  const int*   enc     = (const int*)d_in[4];
  const float* tok_emb = (const float*)d_in[5];
  const float* Wm1     = (const float*)d_in[6];
  const float* Wm2     = (const float*)d_in[7];
  const float* Wp1     = (const float*)d_in[8];
  const float* Wp2     = (const float*)d_in[9];
  const float* Wn1     = (const float*)d_in[10];
  const float* Wn2     = (const float*)d_in[11];
  const float* Wd1     = (const float*)d_in[12];
  const float* Wd2     = (const float*)d_in[13];
  const float* Wd3     = (const float*)d_in[14];
  const float* Wdec    = (const float*)d_in[15];
  float* out = (float*)d_out;
  float* ws  = (float*)d_ws;

  const size_t MN  = (size_t)Gn * 256;   // 778,240
  const size_t MN2 = (size_t)Gn * 512;   // 1,556,480
  size_t o = 0;
  float* xc    = ws + o; o += MN2;
  float* P1    = ws + o; o += MN;
  float* N1    = ws + o; o += MN;
  float* hp    = ws + o; o += MN;
  float* hn    = ws + o; o += MN;
  float* P2    = ws + o; o += MN;
  float* N2    = ws + o; o += MN;
  float* zbuf  = ws + o; o += MN2;
  float* d1    = ws + o; o += MN;
  float* d2    = ws + o; o += MN2;
  float* z3    = ws + o; o += MN;
  float* tb    = ws + o; o += MN;
  float* partP = ws + o; o += 4 * MN;
  float* partN = ws + o; o += 4 * MN;    // total ~17.1M floats = 68.5 MB

  dim3 b256(256);

  // 0) xc[:, :384] = x
  copyx_kernel<<<dim3((Gn * (XC / 4) + 255) / 256), b256, 0, stream>>>(x, xc);
  // 1) smile GCN -> xc[:, 384:512]
  smile_kernel<<<dim3(Gn), b256, 0, stream>>>(mol_adj, enc, tok_emb, Wm1, Wm2, xc);
  // 2) P1 = xc@Wp1 ; N1 = xc@Wn1
  gemm64_kernel<<<dim3(48, 4, 2), b256, 0, stream>>>(xc, xc, Wp1, Wn1, P1, N1, Gn, 256, 512, 0);
  // 3) partials = adj_{pos,neg} @ {P1,N1}  (split-K S=4)
  gemm128_kernel<false, true><<<dim3(24, 2, 8), b256, 0, stream>>>(
      adj_pos, adj_neg, P1, N1, partP, partN, Gn, 256, Gn);
  // 4) hp = relu(sum partP) ; hn = relu(sum partN)
  reduce_kernel<<<dim3(760), b256, 0, stream>>>(partP, hp, 4, Gn, 256, 256, 0, 1);
  reduce_kernel<<<dim3(760), b256, 0, stream>>>(partN, hn, 4, Gn, 256, 256, 0, 1);
  // 5) P2 = hp@Wp2 ; N2 = hn@Wn2
  gemm64_kernel<<<dim3(48, 4, 2), b256, 0, stream>>>(hp, hn, Wp2, Wn2, P2, N2, Gn, 256, 256, 0);
  // 6) partials = adj_{pos,neg} @ {P2,N2}
  gemm128_kernel<false, true><<<dim3(24, 2, 8), b256, 0, stream>>>(
      adj_pos, adj_neg, P2, N2, partP, partN, Gn, 256, Gn);
  // 7) z = [zp | zn]
  reduce_kernel<<<dim3(760), b256, 0, stream>>>(partP, zbuf, 4, Gn, 256, 512, 0, 0);
  reduce_kernel<<<dim3(760), b256, 0, stream>>>(partN, zbuf, 4, Gn, 256, 512, 256, 0);
  // 8) d1 = relu(z@Wd1)
  gemm64_kernel<<<dim3(48, 4, 1), b256, 0, stream>>>(zbuf, zbuf, Wd1, Wd1, d1, d1, Gn, 256, 512, 1);
  // 9) d2 = relu(d1@Wd2)
  gemm64_kernel<<<dim3(48, 8, 1), b256, 0, stream>>>(d1, d1, Wd2, Wd2, d2, d2, Gn, 512, 256, 1);
  // 10) z3 = d2@Wd3
  gemm64_kernel<<<dim3(48, 4, 1), b256, 0, stream>>>(d2, d2, Wd3, Wd3, z3, z3, Gn, 256, 512, 0);
  // 11) tb = z3@Wdec
  gemm64_kernel<<<dim3(48, 4, 1), b256, 0, stream>>>(z3, z3, Wdec, Wdec, tb, tb, Gn, 256, 256, 0);
  // 12) out = tb @ z3^T
  gemm128_kernel<true, false><<<dim3(24, 24, 1), b256, 0, stream>>>(
      tb, tb, z3, z3, out, out, Gn, Gn, 256);
}